// Round 1
// 449.244 us; speedup vs baseline: 1.1304x; 1.1304x over previous
//
#include <hip/hip_runtime.h>

// GlobalRankPooling: out[b,c] = sum_s sort_desc(x[b,c,:])[s] * w[c,s] + bias[c]
// B=32, C=2048, S=1024. One wave per (b,c), 16 elems/lane, i = 16*lane + q.
// Round-6: FUSED single-instruction DPP compare-exchange. Every DPP-reachable
// cross-lane CE (xor1, xor2, xor8) is exactly ONE VALU instruction:
//   v_max_f32 r, -r(dpp cross-lane), r
// (DPP src0 modifier gives the negate for free; no separate v_mov_b32_dpp,
// no tied-old zero-init). Each asm block leads with s_nop 1 to satisfy the
// "VALU write -> DPP read needs 2 wait states" hazard, since the hazard
// recognizer cannot see into inline asm. xor4/xor16 stay on ds_swizzle and
// xor32 on ds_bpermute (LDS pipe is ~idle; their max is 1 VALU either way).

#define C_DIM 2048
#define S_DIM 1024

template <int CTRL>
__device__ __forceinline__ float dppf(float v) {
  return __int_as_float(__builtin_amdgcn_update_dpp(
      0, __float_as_int(v), CTRL, 0xF, 0xF, false));
}
template <int PAT>
__device__ __forceinline__ float swzf(float v) {
  return __int_as_float(__builtin_amdgcn_ds_swizzle(__float_as_int(v), PAT));
}
__device__ __forceinline__ float bperm(int addr, float v) {
  return __int_as_float(__builtin_amdgcn_ds_bpermute(addr, __float_as_int(v)));
}

// One fused cross-lane CE level: r[q] = max(r[q], -dpp(r[q])) for all 16 regs,
// one v_max_f32_dpp per element. s_nop 1 guards the VALU->DPP hazard against
// whatever instruction the scheduler placed immediately before this block.
#define CROSS_ASM(CTRL)                                                        \
  asm volatile(                                                                \
      "s_nop 1\n\t"                                                            \
      "v_max_f32 %0,  -%0,  %0 "  CTRL "\n\t"                                  \
      "v_max_f32 %1,  -%1,  %1 "  CTRL "\n\t"                                  \
      "v_max_f32 %2,  -%2,  %2 "  CTRL "\n\t"                                  \
      "v_max_f32 %3,  -%3,  %3 "  CTRL "\n\t"                                  \
      "v_max_f32 %4,  -%4,  %4 "  CTRL "\n\t"                                  \
      "v_max_f32 %5,  -%5,  %5 "  CTRL "\n\t"                                  \
      "v_max_f32 %6,  -%6,  %6 "  CTRL "\n\t"                                  \
      "v_max_f32 %7,  -%7,  %7 "  CTRL "\n\t"                                  \
      "v_max_f32 %8,  -%8,  %8 "  CTRL "\n\t"                                  \
      "v_max_f32 %9,  -%9,  %9 "  CTRL "\n\t"                                  \
      "v_max_f32 %10, -%10, %10 " CTRL "\n\t"                                  \
      "v_max_f32 %11, -%11, %11 " CTRL "\n\t"                                  \
      "v_max_f32 %12, -%12, %12 " CTRL "\n\t"                                  \
      "v_max_f32 %13, -%13, %13 " CTRL                                         \
      "\n\t"                                                                   \
      "v_max_f32 %14, -%14, %14 " CTRL "\n\t"                                  \
      "v_max_f32 %15, -%15, %15 " CTRL                                         \
      : "+v"(r[0]),  "+v"(r[1]),  "+v"(r[2]),  "+v"(r[3]),                     \
        "+v"(r[4]),  "+v"(r[5]),  "+v"(r[6]),  "+v"(r[7]),                     \
        "+v"(r[8]),  "+v"(r[9]),  "+v"(r[10]), "+v"(r[11]),                    \
        "+v"(r[12]), "+v"(r[13]), "+v"(r[14]), "+v"(r[15]))

// One cross-lane CE step in dual-adjusted space: r = max(r, -p), all lanes.
template <int JL>
__device__ __forceinline__ void cross(float (&r)[16], int addr32) {
  if constexpr (JL == 1) {
    CROSS_ASM("quad_perm:[1,0,3,2] row_mask:0xf bank_mask:0xf");
  } else if constexpr (JL == 2) {
    CROSS_ASM("quad_perm:[2,3,0,1] row_mask:0xf bank_mask:0xf");
  } else if constexpr (JL == 8) {
    CROSS_ASM("row_ror:8 row_mask:0xf bank_mask:0xf");
  } else {
    float p[16];
    #pragma unroll
    for (int q = 0; q < 16; ++q) {
      if constexpr (JL == 4)       p[q] = swzf<0x101F>(r[q]);  // BitMode xor4
      else if constexpr (JL == 16) p[q] = swzf<0x401F>(r[q]);  // BitMode xor16
      else                         p[q] = bperm(addr32, r[q]); // xor32
    }
    #pragma unroll
    for (int q = 0; q < 16; ++q) r[q] = fmaxf(r[q], -p[q]);
  }
}

// In-register bitonic merge j=8,4,2,1; lower reg index takes max.
__device__ __forceinline__ void merge16(float (&r)[16]) {
  #pragma unroll
  for (int j = 8; j >= 1; j >>= 1) {
    #pragma unroll
    for (int q = 0; q < 16; ++q) {
      const int l = q ^ j;
      if (l > q) {
        const float hi = fmaxf(r[q], r[l]);
        const float lo = fminf(r[q], r[l]);
        r[q] = hi; r[l] = lo;
      }
    }
  }
}

__device__ __forceinline__ void flip(float (&r)[16], unsigned m) {
  #pragma unroll
  for (int q = 0; q < 16; ++q)
    r[q] = __int_as_float(__float_as_int(r[q]) ^ (int)m);
}

__global__ __launch_bounds__(256) void rankpool_signspace_kernel(
    const float* __restrict__ x, const float* __restrict__ w,
    const float* __restrict__ bias, float* __restrict__ out) {
  const int t      = threadIdx.x;
  const int lane   = t & 63;
  const int bc     = (blockIdx.x << 2) | (t >> 6);   // one wave per (b,c)
  const int c      = bc & (C_DIM - 1);
  const int addr32 = (lane ^ 32) << 2;               // bpermute byte address
  const unsigned L = (unsigned)lane;
  #define MB(b)      ((L << (31 - (b))) & 0x80000000u)             // lane bit b
  #define MX(bi, bj) (((L << (31-(bi))) ^ (L << (31-(bj)))) & 0x80000000u)

  // ---- load 16 elems/lane (initial permutation irrelevant — we sort) ----
  float r[16];
  {
    const float4* x4 = (const float4*)(x + (size_t)bc * S_DIM);
    #pragma unroll
    for (int q2 = 0; q2 < 4; ++q2) {
      const float4 v = x4[(q2 << 6) + lane];
      r[4*q2+0] = v.x; r[4*q2+1] = v.y; r[4*q2+2] = v.z; r[4*q2+3] = v.w;
    }
  }

  // ---- stages k=2,4,8: in-register, raw space, compile-time directions ----
  #pragma unroll
  for (int k = 2; k <= 8; k <<= 1) {
    #pragma unroll
    for (int j = k >> 1; j >= 1; j >>= 1) {
      #pragma unroll
      for (int q = 0; q < 16; ++q) {
        const int l = q ^ j;
        if (l > q) {
          const bool desc = ((q & k) == 0);
          const float hi = fmaxf(r[q], r[l]);
          const float lo = fminf(r[q], r[l]);
          r[q] = desc ? hi : lo;   // compile-time select
          r[l] = desc ? lo : hi;
        }
      }
    }
  }

  // ---- k=16: enter W16 (flip bit0 lanes), in-register merge ----
  flip(r, MB(0));
  merge16(r);

  // ---- k=32 ----   boundary(b0^b1) ⊕ enterD(b0) = b1
  flip(r, MB(1));
  cross<1>(r, addr32);
  flip(r, MB(0));                       // exit D
  merge16(r);

  // ---- k=64 ----   boundary(b1^b2) ⊕ enterD(b1) = b2
  flip(r, MB(2));
  cross<2>(r, addr32);
  flip(r, MX(1, 0));                    // D=2 -> D=1
  cross<1>(r, addr32);
  flip(r, MB(0));
  merge16(r);

  // ---- k=128 ----  boundary(b2^b3) ⊕ enterD(b2) = b3
  flip(r, MB(3));
  cross<4>(r, addr32);
  flip(r, MX(2, 1));
  cross<2>(r, addr32);
  flip(r, MX(1, 0));
  cross<1>(r, addr32);
  flip(r, MB(0));
  merge16(r);

  // ---- k=256 ----  boundary(b3^b4) ⊕ enterD(b3) = b4
  flip(r, MB(4));
  cross<8>(r, addr32);
  flip(r, MX(3, 2));
  cross<4>(r, addr32);
  flip(r, MX(2, 1));
  cross<2>(r, addr32);
  flip(r, MX(1, 0));
  cross<1>(r, addr32);
  flip(r, MB(0));
  merge16(r);

  // ---- k=512 ----  boundary(b4^b5) ⊕ enterD(b4) = b5
  flip(r, MB(5));
  cross<16>(r, addr32);
  flip(r, MX(4, 3));
  cross<8>(r, addr32);
  flip(r, MX(3, 2));
  cross<4>(r, addr32);
  flip(r, MX(2, 1));
  cross<2>(r, addr32);
  flip(r, MX(1, 0));
  cross<1>(r, addr32);
  flip(r, MB(0));
  merge16(r);

  // ---- k=1024 ---- boundary(b5^b6=b5) ⊕ enterD(b5) = 0 (no flip)
  cross<32>(r, addr32);
  flip(r, MX(5, 4));
  cross<16>(r, addr32);
  flip(r, MX(4, 3));
  cross<8>(r, addr32);
  flip(r, MX(3, 2));
  cross<4>(r, addr32);
  flip(r, MX(2, 1));
  cross<2>(r, addr32);
  flip(r, MX(1, 0));
  cross<1>(r, addr32);
  flip(r, MB(0));
  merge16(r);                           // raw space, fully descending

  // ---- dot with weight row: lane holds sorted[16*lane .. 16*lane+15] ----
  const float4* w4 = (const float4*)(w + (size_t)c * S_DIM);
  float acc = 0.f;
  #pragma unroll
  for (int q2 = 0; q2 < 4; ++q2) {
    const float4 wv = w4[(lane << 2) + q2];
    acc += r[4*q2+0] * wv.x + r[4*q2+1] * wv.y +
           r[4*q2+2] * wv.z + r[4*q2+3] * wv.w;
  }

  // ---- butterfly wave reduction (same single-inst movers) ----
  acc += dppf<0xB1>(acc);
  acc += dppf<0x4E>(acc);
  acc += swzf<0x101F>(acc);
  acc += dppf<0x128>(acc);
  acc += swzf<0x401F>(acc);
  acc += bperm(addr32, acc);
  if (lane == 0) out[bc] = acc + bias[c];

  #undef MB
  #undef MX
}

extern "C" void kernel_launch(void* const* d_in, const int* in_sizes, int n_in,
                              void* d_out, int out_size, void* d_ws, size_t ws_size,
                              hipStream_t stream) {
  const float* x    = (const float*)d_in[0];   // (32, 2048, 32, 32) f32
  const float* w    = (const float*)d_in[1];   // (2048, 1, 1024)   f32
  const float* bias = (const float*)d_in[2];   // (2048,)           f32
  float* out        = (float*)d_out;           // (32, 2048, 1)     f32

  rankpool_signspace_kernel<<<(32 * C_DIM) / 4, 256, 0, stream>>>(x, w, bias, out);
}

// Round 2
// 375.892 us; speedup vs baseline: 1.3510x; 1.1951x over previous
//
#include <hip/hip_runtime.h>

// GlobalRankPooling: out[b,c] = sum_s sort_desc(x[b,c,:])[s] * w[c,s] + bias[c]
// B=32, C=2048, S=1024.
// Round-7: PACKED DUAL-CHANNEL f16 SORT. One wave sorts TWO channels at once:
// r[q] = (half_lo = chanA elem, half_hi = chanB elem). Every compare-exchange
// is one v_pk_max_f16/v_pk_min_f16 serving both channels; every convention
// flip is one v_xor_b32 (0x80008000-style masks) serving both. Cross-lane CEs:
//   v_mov_b32_dpp tmp, r  ;  v_pk_max_f16 r, r, tmp neg_lo:[0,1] neg_hi:[0,1]
// (xor1/2/8 via DPP; xor4/16 via ds_swizzle; xor32 via ds_bpermute).
// Initial per-lane 16-sort: Batcher merge-exchange, 63 CEs (vs bitonic 80).
// Weights + accumulation stay f32; only sort values are f16 (RTN converts).

#define C_DIM 2048
#define S_DIM 1024

typedef _Float16 h2 __attribute__((ext_vector_type(2)));

__device__ __forceinline__ h2  toh2(int x) { return __builtin_bit_cast(h2, x); }
__device__ __forceinline__ int toi(h2 x)   { return __builtin_bit_cast(int, x); }

template <int CTRL>
__device__ __forceinline__ float dppf(float v) {
  return __int_as_float(__builtin_amdgcn_update_dpp(
      0, __float_as_int(v), CTRL, 0xF, 0xF, false));
}
template <int PAT>
__device__ __forceinline__ float swzf(float v) {
  return __int_as_float(__builtin_amdgcn_ds_swizzle(__float_as_int(v), PAT));
}
__device__ __forceinline__ float bpermf(int addr, float v) {
  return __int_as_float(__builtin_amdgcn_ds_bpermute(addr, __float_as_int(v)));
}

// Intra-lane CE (descending: max at a, min at b), both halves independently.
#define CE(a, b)                                                \
  {                                                             \
    const h2 va = toh2(r[a]), vb = toh2(r[b]);                  \
    r[a] = toi(__builtin_elementwise_max(va, vb));              \
    r[b] = toi(__builtin_elementwise_min(va, vb));              \
  }

// 8-register DPP cross chunk: tmp = dpp(r); r = pk_max(r, -tmp).
// s_nop 1 covers the VALU-write -> DPP-read hazard at block entry.
#define CROSS_DPP8(CTRL, r0, r1, r2, r3, r4, r5, r6, r7)                       \
  {                                                                            \
    int t0, t1, t2, t3, t4, t5, t6, t7;                                        \
    asm volatile(                                                              \
        "s_nop 1\n\t"                                                          \
        "v_mov_b32 %8,  %0 " CTRL "\n\t"                                       \
        "v_mov_b32 %9,  %1 " CTRL "\n\t"                                       \
        "v_mov_b32 %10, %2 " CTRL "\n\t"                                       \
        "v_mov_b32 %11, %3 " CTRL "\n\t"                                       \
        "v_mov_b32 %12, %4 " CTRL "\n\t"                                       \
        "v_mov_b32 %13, %5 " CTRL "\n\t"                                       \
        "v_mov_b32 %14, %6 " CTRL "\n\t"                                       \
        "v_mov_b32 %15, %7 " CTRL "\n\t"                                       \
        "v_pk_max_f16 %0, %0, %8  neg_lo:[0,1] neg_hi:[0,1]\n\t"               \
        "v_pk_max_f16 %1, %1, %9  neg_lo:[0,1] neg_hi:[0,1]\n\t"               \
        "v_pk_max_f16 %2, %2, %10 neg_lo:[0,1] neg_hi:[0,1]\n\t"               \
        "v_pk_max_f16 %3, %3, %11 neg_lo:[0,1] neg_hi:[0,1]\n\t"               \
        "v_pk_max_f16 %4, %4, %12 neg_lo:[0,1] neg_hi:[0,1]\n\t"               \
        "v_pk_max_f16 %5, %5, %13 neg_lo:[0,1] neg_hi:[0,1]\n\t"               \
        "v_pk_max_f16 %6, %6, %14 neg_lo:[0,1] neg_hi:[0,1]\n\t"               \
        "v_pk_max_f16 %7, %7, %15 neg_lo:[0,1] neg_hi:[0,1]"                   \
        : "+v"(r0), "+v"(r1), "+v"(r2), "+v"(r3),                              \
          "+v"(r4), "+v"(r5), "+v"(r6), "+v"(r7),                              \
          "=&v"(t0), "=&v"(t1), "=&v"(t2), "=&v"(t3),                          \
          "=&v"(t4), "=&v"(t5), "=&v"(t6), "=&v"(t7));                         \
  }

#define CROSS_DPP(CTRL)                                                        \
  CROSS_DPP8(CTRL, r[0], r[1], r[2], r[3], r[4], r[5], r[6], r[7]);            \
  CROSS_DPP8(CTRL, r[8], r[9], r[10], r[11], r[12], r[13], r[14], r[15])

// Cross-lane CE level in dual sign space (all variants): r = pk_max(r, -p).
template <int JL>
__device__ __forceinline__ void cross(int (&r)[16], int addr32) {
  if constexpr (JL == 1) {
    CROSS_DPP("quad_perm:[1,0,3,2] row_mask:0xf bank_mask:0xf");
  } else if constexpr (JL == 2) {
    CROSS_DPP("quad_perm:[2,3,0,1] row_mask:0xf bank_mask:0xf");
  } else if constexpr (JL == 8) {
    CROSS_DPP("row_ror:8 row_mask:0xf bank_mask:0xf");
  } else {
    int p[16];
    #pragma unroll
    for (int q = 0; q < 16; ++q) {
      if constexpr (JL == 4)       p[q] = __builtin_amdgcn_ds_swizzle(r[q], 0x101F);
      else if constexpr (JL == 16) p[q] = __builtin_amdgcn_ds_swizzle(r[q], 0x401F);
      else                         p[q] = __builtin_amdgcn_ds_bpermute(addr32, r[q]);
    }
    #pragma unroll
    for (int q = 0; q < 16; ++q)
      asm volatile("v_pk_max_f16 %0, %0, %1 neg_lo:[0,1] neg_hi:[0,1]"
                   : "+v"(r[q]) : "v"(p[q]));
  }
}

// In-register bitonic merge j=8,4,2,1; lower reg index takes max (both halves).
__device__ __forceinline__ void merge16(int (&r)[16]) {
  #pragma unroll
  for (int j = 8; j >= 1; j >>= 1) {
    #pragma unroll
    for (int q = 0; q < 16; ++q) {
      const int l = q ^ j;
      if (l > q) CE(q, l);
    }
  }
}

__device__ __forceinline__ void flip(int (&r)[16], int m) {
  #pragma unroll
  for (int q = 0; q < 16; ++q) r[q] ^= m;
}

__device__ __forceinline__ int pack2(float a, float b) {
  h2 t;
  t.x = (_Float16)a;   // RTN
  t.y = (_Float16)b;   // RTN
  return toi(t);
}

// Batcher merge-exchange network for 16 elements, 63 CEs (Knuth Alg. 5.2.2M),
// mirrored to descending polarity.
__device__ __forceinline__ void sort16_desc(int (&r)[16]) {
  // p=8
  CE(0,8) CE(1,9) CE(2,10) CE(3,11) CE(4,12) CE(5,13) CE(6,14) CE(7,15)
  // p=4
  CE(0,4) CE(1,5) CE(2,6) CE(3,7) CE(8,12) CE(9,13) CE(10,14) CE(11,15)
  CE(4,8) CE(5,9) CE(6,10) CE(7,11)
  // p=2
  CE(0,2) CE(1,3) CE(4,6) CE(5,7) CE(8,10) CE(9,11) CE(12,14) CE(13,15)
  CE(2,8) CE(3,9) CE(6,12) CE(7,13)
  CE(2,4) CE(3,5) CE(6,8) CE(7,9) CE(10,12) CE(11,13)
  // p=1
  CE(0,1) CE(2,3) CE(4,5) CE(6,7) CE(8,9) CE(10,11) CE(12,13) CE(14,15)
  CE(1,8) CE(3,10) CE(5,12) CE(7,14)
  CE(1,4) CE(3,6) CE(5,8) CE(7,10) CE(9,12) CE(11,14)
  CE(1,2) CE(3,4) CE(5,6) CE(7,8) CE(9,10) CE(11,12) CE(13,14)
}

__global__ __launch_bounds__(256) void rankpool_pk2_kernel(
    const float* __restrict__ x, const float* __restrict__ w,
    const float* __restrict__ bias, float* __restrict__ out) {
  const int t      = threadIdx.x;
  const int lane   = t & 63;
  const int wv     = (blockIdx.x << 2) | (t >> 6);   // one wave per channel PAIR
  const int bc0    = wv << 1;                        // even (b,c) index (chan A)
  const int cA     = bc0 & (C_DIM - 1);              // cB = cA + 1 (never wraps)
  const int addr32 = (lane ^ 32) << 2;               // bpermute byte address
  const unsigned L = (unsigned)lane;

  // Packed sign masks: 0x80008000 in lanes where the lane-bit condition holds.
  #define MBP(b)      ({ unsigned m_ = (L << (31-(b))) & 0x80000000u; (int)(m_ | (m_ >> 16)); })
  #define MXP(bi, bj) ({ unsigned m_ = ((L << (31-(bi))) ^ (L << (31-(bj)))) & 0x80000000u; (int)(m_ | (m_ >> 16)); })

  // ---- load 16 f32 elems/lane for BOTH channels, pack to f16 pairs ----
  int r[16];
  {
    const float4* x4a = (const float4*)(x + (size_t)bc0 * S_DIM);
    const float4* x4b = x4a + (S_DIM / 4);
    #pragma unroll
    for (int q2 = 0; q2 < 4; ++q2) {
      const float4 va = x4a[(q2 << 6) + lane];
      const float4 vb = x4b[(q2 << 6) + lane];
      r[4*q2+0] = pack2(va.x, vb.x);
      r[4*q2+1] = pack2(va.y, vb.y);
      r[4*q2+2] = pack2(va.z, vb.z);
      r[4*q2+3] = pack2(va.w, vb.w);
    }
  }

  // ---- per-lane 16-sort descending in dual space (convention b0) ----
  flip(r, MBP(0));
  sort16_desc(r);

  // ---- k=32 ----
  flip(r, MBP(1));
  cross<1>(r, addr32);
  flip(r, MBP(0));
  merge16(r);

  // ---- k=64 ----
  flip(r, MBP(2));
  cross<2>(r, addr32);
  flip(r, MXP(1, 0));
  cross<1>(r, addr32);
  flip(r, MBP(0));
  merge16(r);

  // ---- k=128 ----
  flip(r, MBP(3));
  cross<4>(r, addr32);
  flip(r, MXP(2, 1));
  cross<2>(r, addr32);
  flip(r, MXP(1, 0));
  cross<1>(r, addr32);
  flip(r, MBP(0));
  merge16(r);

  // ---- k=256 ----
  flip(r, MBP(4));
  cross<8>(r, addr32);
  flip(r, MXP(3, 2));
  cross<4>(r, addr32);
  flip(r, MXP(2, 1));
  cross<2>(r, addr32);
  flip(r, MXP(1, 0));
  cross<1>(r, addr32);
  flip(r, MBP(0));
  merge16(r);

  // ---- k=512 ----
  flip(r, MBP(5));
  cross<16>(r, addr32);
  flip(r, MXP(4, 3));
  cross<8>(r, addr32);
  flip(r, MXP(3, 2));
  cross<4>(r, addr32);
  flip(r, MXP(2, 1));
  cross<2>(r, addr32);
  flip(r, MXP(1, 0));
  cross<1>(r, addr32);
  flip(r, MBP(0));
  merge16(r);

  // ---- k=1024 ---- (no entry flip: b5 boundary ⊕ D=0 lands on current conv)
  cross<32>(r, addr32);
  flip(r, MXP(5, 4));
  cross<16>(r, addr32);
  flip(r, MXP(4, 3));
  cross<8>(r, addr32);
  flip(r, MXP(3, 2));
  cross<4>(r, addr32);
  flip(r, MXP(2, 1));
  cross<2>(r, addr32);
  flip(r, MXP(1, 0));
  cross<1>(r, addr32);
  flip(r, MBP(0));
  merge16(r);   // raw space; both halves fully descending

  // ---- dual dot with f32 weight rows ----
  const float4* w4a = (const float4*)(w + (size_t)cA * S_DIM);
  const float4* w4b = (const float4*)(w + (size_t)(cA + 1) * S_DIM);
  float accA = 0.f, accB = 0.f;
  #pragma unroll
  for (int q2 = 0; q2 < 4; ++q2) {
    const float4 wa = w4a[(lane << 2) + q2];
    const float4 wb = w4b[(lane << 2) + q2];
    const float* pa = (const float*)&wa;
    const float* pb = (const float*)&wb;
    #pragma unroll
    for (int j = 0; j < 4; ++j) {
      const h2 v = toh2(r[4*q2 + j]);
      accA = fmaf((float)v.x, pa[j], accA);
      accB = fmaf((float)v.y, pb[j], accB);
    }
  }

  // ---- butterfly wave reductions ----
  accA += dppf<0xB1>(accA);   accB += dppf<0xB1>(accB);
  accA += dppf<0x4E>(accA);   accB += dppf<0x4E>(accB);
  accA += swzf<0x101F>(accA); accB += swzf<0x101F>(accB);
  accA += dppf<0x128>(accA);  accB += dppf<0x128>(accB);
  accA += swzf<0x401F>(accA); accB += swzf<0x401F>(accB);
  accA += bpermf(addr32, accA); accB += bpermf(addr32, accB);

  if (lane == 0) {
    const float2 bv = *(const float2*)(bias + cA);
    float2 o;
    o.x = accA + bv.x;
    o.y = accB + bv.y;
    *(float2*)(out + bc0) = o;
  }

  #undef MBP
  #undef MXP
}

extern "C" void kernel_launch(void* const* d_in, const int* in_sizes, int n_in,
                              void* d_out, int out_size, void* d_ws, size_t ws_size,
                              hipStream_t stream) {
  const float* x    = (const float*)d_in[0];   // (32, 2048, 32, 32) f32
  const float* w    = (const float*)d_in[1];   // (2048, 1, 1024)   f32
  const float* bias = (const float*)d_in[2];   // (2048,)           f32
  float* out        = (float*)d_out;           // (32, 2048, 1)     f32

  // One wave per channel pair: 32*2048/2 waves, 4 waves/block.
  rankpool_pk2_kernel<<<(32 * C_DIM) / 2 / 4, 256, 0, stream>>>(x, w, bias, out);
}

// Round 4
// 372.264 us; speedup vs baseline: 1.3642x; 1.0097x over previous
//
#include <hip/hip_runtime.h>

// GlobalRankPooling: out[b,c] = sum_s sort_desc(x[b,c,:])[s] * w[c,s] + bias[c]
// B=32, C=2048, S=1024.
// Round-9: R8 with the cvt_pkrtz type fixed (bit_cast the builtin's native
// __fp16x2 return directly to int). Packed dual-channel f16 bitonic sort:
//  - every CE is one v_pk_max/v_pk_min serving both channels
//  - convention flips are one v_xor_b32 per reg (0x80008000 masks)
//  - xor1/2/8 cross via DPP mov + pk_max neg; xor4/16 ds_swizzle; xor32 bperm
//  - input pack via v_cvt_pkrtz_f16_f32 (1 op)
//  - dot epilogue via v_fma_mix_f32 (f16 half as direct f32 operand)

#define C_DIM 2048
#define S_DIM 1024

typedef _Float16 h2 __attribute__((ext_vector_type(2)));

__device__ __forceinline__ h2  toh2(int x) { return __builtin_bit_cast(h2, x); }
__device__ __forceinline__ int toi(h2 x)   { return __builtin_bit_cast(int, x); }

template <int CTRL>
__device__ __forceinline__ float dppf(float v) {
  return __int_as_float(__builtin_amdgcn_update_dpp(
      0, __float_as_int(v), CTRL, 0xF, 0xF, false));
}
template <int PAT>
__device__ __forceinline__ float swzf(float v) {
  return __int_as_float(__builtin_amdgcn_ds_swizzle(__float_as_int(v), PAT));
}
__device__ __forceinline__ float bpermf(int addr, float v) {
  return __int_as_float(__builtin_amdgcn_ds_bpermute(addr, __float_as_int(v)));
}

// Intra-lane CE (descending: max at a, min at b), both halves independently.
#define CE(a, b)                                                \
  {                                                             \
    const h2 va = toh2(r[a]), vb = toh2(r[b]);                  \
    r[a] = toi(__builtin_elementwise_max(va, vb));              \
    r[b] = toi(__builtin_elementwise_min(va, vb));              \
  }

// 8-register DPP cross chunk: tmp = dpp(r); r = pk_max(r, -tmp).
// s_nop 1 covers the VALU-write -> DPP-read hazard at block entry.
#define CROSS_DPP8(CTRL, r0, r1, r2, r3, r4, r5, r6, r7)                       \
  {                                                                            \
    int t0, t1, t2, t3, t4, t5, t6, t7;                                        \
    asm volatile(                                                              \
        "s_nop 1\n\t"                                                          \
        "v_mov_b32 %8,  %0 " CTRL "\n\t"                                       \
        "v_mov_b32 %9,  %1 " CTRL "\n\t"                                       \
        "v_mov_b32 %10, %2 " CTRL "\n\t"                                       \
        "v_mov_b32 %11, %3 " CTRL "\n\t"                                       \
        "v_mov_b32 %12, %4 " CTRL "\n\t"                                       \
        "v_mov_b32 %13, %5 " CTRL "\n\t"                                       \
        "v_mov_b32 %14, %6 " CTRL "\n\t"                                       \
        "v_mov_b32 %15, %7 " CTRL "\n\t"                                       \
        "v_pk_max_f16 %0, %0, %8  neg_lo:[0,1] neg_hi:[0,1]\n\t"               \
        "v_pk_max_f16 %1, %1, %9  neg_lo:[0,1] neg_hi:[0,1]\n\t"               \
        "v_pk_max_f16 %2, %2, %10 neg_lo:[0,1] neg_hi:[0,1]\n\t"               \
        "v_pk_max_f16 %3, %3, %11 neg_lo:[0,1] neg_hi:[0,1]\n\t"               \
        "v_pk_max_f16 %4, %4, %12 neg_lo:[0,1] neg_hi:[0,1]\n\t"               \
        "v_pk_max_f16 %5, %5, %13 neg_lo:[0,1] neg_hi:[0,1]\n\t"               \
        "v_pk_max_f16 %6, %6, %14 neg_lo:[0,1] neg_hi:[0,1]\n\t"               \
        "v_pk_max_f16 %7, %7, %15 neg_lo:[0,1] neg_hi:[0,1]"                   \
        : "+v"(r0), "+v"(r1), "+v"(r2), "+v"(r3),                              \
          "+v"(r4), "+v"(r5), "+v"(r6), "+v"(r7),                              \
          "=&v"(t0), "=&v"(t1), "=&v"(t2), "=&v"(t3),                          \
          "=&v"(t4), "=&v"(t5), "=&v"(t6), "=&v"(t7));                         \
  }

#define CROSS_DPP(CTRL)                                                        \
  CROSS_DPP8(CTRL, r[0], r[1], r[2], r[3], r[4], r[5], r[6], r[7]);            \
  CROSS_DPP8(CTRL, r[8], r[9], r[10], r[11], r[12], r[13], r[14], r[15])

// Cross-lane CE level in dual sign space (all variants): r = pk_max(r, -p).
template <int JL>
__device__ __forceinline__ void cross(int (&r)[16], int addr32) {
  if constexpr (JL == 1) {
    CROSS_DPP("quad_perm:[1,0,3,2] row_mask:0xf bank_mask:0xf");
  } else if constexpr (JL == 2) {
    CROSS_DPP("quad_perm:[2,3,0,1] row_mask:0xf bank_mask:0xf");
  } else if constexpr (JL == 8) {
    CROSS_DPP("row_ror:8 row_mask:0xf bank_mask:0xf");
  } else {
    int p[16];
    #pragma unroll
    for (int q = 0; q < 16; ++q) {
      if constexpr (JL == 4)       p[q] = __builtin_amdgcn_ds_swizzle(r[q], 0x101F);
      else if constexpr (JL == 16) p[q] = __builtin_amdgcn_ds_swizzle(r[q], 0x401F);
      else                         p[q] = __builtin_amdgcn_ds_bpermute(addr32, r[q]);
    }
    #pragma unroll
    for (int q = 0; q < 16; ++q)
      asm volatile("v_pk_max_f16 %0, %0, %1 neg_lo:[0,1] neg_hi:[0,1]"
                   : "+v"(r[q]) : "v"(p[q]));
  }
}

// In-register bitonic merge j=8,4,2,1; lower reg index takes max (both halves).
__device__ __forceinline__ void merge16(int (&r)[16]) {
  #pragma unroll
  for (int j = 8; j >= 1; j >>= 1) {
    #pragma unroll
    for (int q = 0; q < 16; ++q) {
      const int l = q ^ j;
      if (l > q) CE(q, l);
    }
  }
}

__device__ __forceinline__ void flip(int (&r)[16], int m) {
  #pragma unroll
  for (int q = 0; q < 16; ++q) r[q] ^= m;
}

// One-instruction pack: v_cvt_pkrtz_f16_f32. RTZ (vs RTN) shifts keys <=1ulp;
// ordering is consistent (all comparisons see the same rounded keys).
// NB: the builtin returns __fp16x2 (distinct from _Float16x2) — bit_cast it
// straight to int.
__device__ __forceinline__ int pack2(float a, float b) {
  return __builtin_bit_cast(int, __builtin_amdgcn_cvt_pkrtz(a, b));
}

// Batcher merge-exchange network for 16 elements, 63 CEs (Knuth Alg. 5.2.2M),
// mirrored to descending polarity.
__device__ __forceinline__ void sort16_desc(int (&r)[16]) {
  // p=8
  CE(0,8) CE(1,9) CE(2,10) CE(3,11) CE(4,12) CE(5,13) CE(6,14) CE(7,15)
  // p=4
  CE(0,4) CE(1,5) CE(2,6) CE(3,7) CE(8,12) CE(9,13) CE(10,14) CE(11,15)
  CE(4,8) CE(5,9) CE(6,10) CE(7,11)
  // p=2
  CE(0,2) CE(1,3) CE(4,6) CE(5,7) CE(8,10) CE(9,11) CE(12,14) CE(13,15)
  CE(2,8) CE(3,9) CE(6,12) CE(7,13)
  CE(2,4) CE(3,5) CE(6,8) CE(7,9) CE(10,12) CE(11,13)
  // p=1
  CE(0,1) CE(2,3) CE(4,5) CE(6,7) CE(8,9) CE(10,11) CE(12,13) CE(14,15)
  CE(1,8) CE(3,10) CE(5,12) CE(7,14)
  CE(1,4) CE(3,6) CE(5,8) CE(7,10) CE(9,12) CE(11,14)
  CE(1,2) CE(3,4) CE(5,6) CE(7,8) CE(9,10) CE(11,12) CE(13,14)
}

__global__ __launch_bounds__(256) void rankpool_pk2_kernel(
    const float* __restrict__ x, const float* __restrict__ w,
    const float* __restrict__ bias, float* __restrict__ out) {
  const int t      = threadIdx.x;
  const int lane   = t & 63;
  const int wv     = (blockIdx.x << 2) | (t >> 6);   // one wave per channel PAIR
  const int bc0    = wv << 1;                        // even (b,c) index (chan A)
  const int cA     = bc0 & (C_DIM - 1);              // cB = cA + 1 (never wraps)
  const int addr32 = (lane ^ 32) << 2;               // bpermute byte address
  const unsigned L = (unsigned)lane;

  // Packed sign masks: 0x80008000 in lanes where the lane-bit condition holds.
  #define MBP(b)      ({ unsigned m_ = (L << (31-(b))) & 0x80000000u; (int)(m_ | (m_ >> 16)); })
  #define MXP(bi, bj) ({ unsigned m_ = ((L << (31-(bi))) ^ (L << (31-(bj)))) & 0x80000000u; (int)(m_ | (m_ >> 16)); })

  // ---- load 16 f32 elems/lane for BOTH channels, pack to f16 pairs ----
  int r[16];
  {
    const float4* x4a = (const float4*)(x + (size_t)bc0 * S_DIM);
    const float4* x4b = x4a + (S_DIM / 4);
    #pragma unroll
    for (int q2 = 0; q2 < 4; ++q2) {
      const float4 va = x4a[(q2 << 6) + lane];
      const float4 vb = x4b[(q2 << 6) + lane];
      r[4*q2+0] = pack2(va.x, vb.x);
      r[4*q2+1] = pack2(va.y, vb.y);
      r[4*q2+2] = pack2(va.z, vb.z);
      r[4*q2+3] = pack2(va.w, vb.w);
    }
  }

  // ---- per-lane 16-sort descending in dual space (convention b0) ----
  flip(r, MBP(0));
  sort16_desc(r);

  // ---- k=32 ----
  flip(r, MBP(1));
  cross<1>(r, addr32);
  flip(r, MBP(0));
  merge16(r);

  // ---- k=64 ----
  flip(r, MBP(2));
  cross<2>(r, addr32);
  flip(r, MXP(1, 0));
  cross<1>(r, addr32);
  flip(r, MBP(0));
  merge16(r);

  // ---- k=128 ----
  flip(r, MBP(3));
  cross<4>(r, addr32);
  flip(r, MXP(2, 1));
  cross<2>(r, addr32);
  flip(r, MXP(1, 0));
  cross<1>(r, addr32);
  flip(r, MBP(0));
  merge16(r);

  // ---- k=256 ----
  flip(r, MBP(4));
  cross<8>(r, addr32);
  flip(r, MXP(3, 2));
  cross<4>(r, addr32);
  flip(r, MXP(2, 1));
  cross<2>(r, addr32);
  flip(r, MXP(1, 0));
  cross<1>(r, addr32);
  flip(r, MBP(0));
  merge16(r);

  // ---- k=512 ----
  flip(r, MBP(5));
  cross<16>(r, addr32);
  flip(r, MXP(4, 3));
  cross<8>(r, addr32);
  flip(r, MXP(3, 2));
  cross<4>(r, addr32);
  flip(r, MXP(2, 1));
  cross<2>(r, addr32);
  flip(r, MXP(1, 0));
  cross<1>(r, addr32);
  flip(r, MBP(0));
  merge16(r);

  // ---- k=1024 ---- (no entry flip: b5 boundary ⊕ D=0 lands on current conv)
  cross<32>(r, addr32);
  flip(r, MXP(5, 4));
  cross<16>(r, addr32);
  flip(r, MXP(4, 3));
  cross<8>(r, addr32);
  flip(r, MXP(3, 2));
  cross<4>(r, addr32);
  flip(r, MXP(2, 1));
  cross<2>(r, addr32);
  flip(r, MXP(1, 0));
  cross<1>(r, addr32);
  flip(r, MBP(0));
  merge16(r);   // raw space; both halves fully descending

  // ---- dual dot with f32 weight rows via v_fma_mix_f32 ----
  // src0 = packed f16 pair (op_sel picks half), src1 = f32 weight, src2 = acc.
  const float4* w4a = (const float4*)(w + (size_t)cA * S_DIM);
  const float4* w4b = (const float4*)(w + (size_t)(cA + 1) * S_DIM);
  float accA = 0.f, accB = 0.f;
  #pragma unroll
  for (int q2 = 0; q2 < 4; ++q2) {
    const float4 wa = w4a[(lane << 2) + q2];
    const float4 wb = w4b[(lane << 2) + q2];
    const float* pa = (const float*)&wa;
    const float* pb = (const float*)&wb;
    #pragma unroll
    for (int j = 0; j < 4; ++j) {
      asm("v_fma_mix_f32 %0, %1, %2, %0 op_sel_hi:[1,0,0]"
          : "+v"(accA) : "v"(r[4*q2 + j]), "v"(pa[j]));
      asm("v_fma_mix_f32 %0, %1, %2, %0 op_sel:[1,0,0] op_sel_hi:[1,0,0]"
          : "+v"(accB) : "v"(r[4*q2 + j]), "v"(pb[j]));
    }
  }

  // ---- butterfly wave reductions ----
  accA += dppf<0xB1>(accA);   accB += dppf<0xB1>(accB);
  accA += dppf<0x4E>(accA);   accB += dppf<0x4E>(accB);
  accA += swzf<0x101F>(accA); accB += swzf<0x101F>(accB);
  accA += dppf<0x128>(accA);  accB += dppf<0x128>(accB);
  accA += swzf<0x401F>(accA); accB += swzf<0x401F>(accB);
  accA += bpermf(addr32, accA); accB += bpermf(addr32, accB);

  if (lane == 0) {
    const float2 bv = *(const float2*)(bias + cA);
    float2 o;
    o.x = accA + bv.x;
    o.y = accB + bv.y;
    *(float2*)(out + bc0) = o;
  }

  #undef MBP
  #undef MXP
}

extern "C" void kernel_launch(void* const* d_in, const int* in_sizes, int n_in,
                              void* d_out, int out_size, void* d_ws, size_t ws_size,
                              hipStream_t stream) {
  const float* x    = (const float*)d_in[0];   // (32, 2048, 32, 32) f32
  const float* w    = (const float*)d_in[1];   // (2048, 1, 1024)   f32
  const float* bias = (const float*)d_in[2];   // (2048,)           f32
  float* out        = (float*)d_out;           // (32, 2048, 1)     f32

  // One wave per channel pair: 32*2048/2 waves, 4 waves/block.
  rankpool_pk2_kernel<<<(32 * C_DIM) / 2 / 4, 256, 0, stream>>>(x, w, bias, out);
}